// Round 4
// baseline (1368.602 us; speedup 1.0000x reference)
//
#include <hip/hip_runtime.h>

#define WAVE 64
constexpr int Cc = 128;  // in_channels (fixed by problem: C=128)

// ---------------- per-node dot products: xw1[u] = x[u]·w[0:C] + b, xw2[u] = x[u]·w[C:2C]
__global__ void k_node_dots(const float* __restrict__ x, const float* __restrict__ w,
                            const float* __restrict__ bptr, float* __restrict__ xw1,
                            float* __restrict__ xw2, int N) {
  int wid = (blockIdx.x * blockDim.x + threadIdx.x) >> 6;
  int lane = threadIdx.x & (WAVE - 1);
  if (wid >= N) return;
  const float* xr = x + (size_t)wid * Cc;
  float a = xr[lane], c2 = xr[lane + 64];
  float s1 = a * w[lane] + c2 * w[lane + 64];
  float s2 = a * w[lane + 128] + c2 * w[lane + 192];
#pragma unroll
  for (int off = 32; off >= 1; off >>= 1) {
    s1 += __shfl_xor(s1, off);
    s2 += __shfl_xor(s2, off);
  }
  if (lane == 0) {
    xw1[wid] = s1 + bptr[0];
    xw2[wid] = s2;
  }
}

// ---------------- edge scores + contracted-edge compaction + contracted degree
__global__ void k_edge_score(const int* __restrict__ src, const int* __restrict__ dst,
                             const float* __restrict__ xw1, const float* __restrict__ xw2,
                             float* __restrict__ score, int2* __restrict__ cedge,
                             int* __restrict__ count, int* __restrict__ deg, int E,
                             int do_compact) {
  int e = blockIdx.x * blockDim.x + threadIdx.x;
  int lane = threadIdx.x & 63;
  int s = 0, d = 0;
  bool con = false;
  if (e < E) {
    s = src[e];
    d = dst[e];
    float arg = xw1[s] + xw2[d];  // xw1 already includes bias
    score[e] = tanhf(arg);
    con = arg > 0.0f;  // tanh(arg) > 0  <=>  arg > 0 (exact)
    if (con) {
      atomicAdd(&deg[s], 1);
      atomicAdd(&deg[d], 1);
    }
  }
  if (!do_compact) return;
  unsigned long long m = __ballot(con);
  int cnt = __popcll(m);
  if (cnt == 0) return;
  int leader = __ffsll((unsigned long long)m) - 1;
  int base = 0;
  if (lane == leader) base = atomicAdd(count, cnt);
  base = __shfl(base, leader);
  if (con) {
    int pfx = __popcll(m & ((1ull << lane) - 1ull));
    cedge[base + pfx] = make_int2(s, d);
  }
}

__global__ void k_iota(int* __restrict__ lab, int N) {
  int i = blockIdx.x * blockDim.x + threadIdx.x;
  if (i < N) lab[i] = i;
}

// relax over compacted contracted edges
__global__ void k_relax(const int2* __restrict__ ce, const int* __restrict__ count,
                        int* __restrict__ lab) {
  int i = blockIdx.x * blockDim.x + threadIdx.x;
  if (i >= *count) return;
  int2 p = ce[i];
  int a = lab[p.x], b = lab[p.y];
  if (a < b) atomicMin(&lab[p.y], a);
  else if (b < a) atomicMin(&lab[p.x], b);
}

// relax without compaction (ws-size fallback)
__global__ void k_relax_full(const int* __restrict__ src, const int* __restrict__ dst,
                             const float* __restrict__ score, int* __restrict__ lab, int E) {
  int i = blockIdx.x * blockDim.x + threadIdx.x;
  if (i >= E) return;
  if (!(score[i] > 0.0f)) return;
  int a = lab[src[i]], b = lab[dst[i]];
  if (a < b) atomicMin(&lab[dst[i]], a);
  else if (b < a) atomicMin(&lab[src[i]], b);
}

// in-place pointer jump (labels monotone non-increasing -> race-safe)
__global__ void k_jump(int* __restrict__ lab, int N) {
  int i = blockIdx.x * blockDim.x + threadIdx.x;
  if (i >= N) return;
  int a = lab[i];
  int b = lab[a];
  if (b < a) lab[i] = b;
}

// sx[src] += score * x[dst] ; one wave per edge, 128 cols
__global__ void k_sx(const int* __restrict__ src, const int* __restrict__ dst,
                     const float* __restrict__ score, const float* __restrict__ x,
                     float* __restrict__ sx, int E) {
  int wid = (blockIdx.x * blockDim.x + threadIdx.x) >> 6;
  int lane = threadIdx.x & 63;
  if (wid >= E) return;
  int s = src[wid], d = dst[wid];
  float t = score[wid];
  const float* xr = x + (size_t)d * Cc;
  float* sr = sx + (size_t)s * Cc;
  atomicAdd(&sr[lane], t * xr[lane]);
  atomicAdd(&sr[lane + 64], t * xr[lane + 64]);
}

// x_out[cluster] += sx (+ x for singles), run-length compressed along node axis
__global__ void k_segsum(const float* __restrict__ sx, const float* __restrict__ x,
                         const int* __restrict__ lab, const int* __restrict__ deg,
                         float* __restrict__ xout, int N) {
  const int CHUNK = 128;
  int lane = threadIdx.x & 63;
  int j = (blockIdx.y << 6) | lane;
  int u0 = blockIdx.x * CHUNK;
  if (u0 >= N) return;
  int u1 = min(u0 + CHUNK, N);
  int prevc = lab[u0];
  float acc = 0.f;
  for (int u = u0; u < u1; ++u) {
    int c = lab[u];
    float v = sx[(size_t)u * Cc + j];
    if (deg[u] == 0) v += x[(size_t)u * Cc + j];
    if (c != prevc) {
      atomicAdd(&xout[(size_t)prevc * Cc + j], acc);
      acc = 0.f;
      prevc = c;
    }
    acc += v;
  }
  atomicAdd(&xout[(size_t)prevc * Cc + j], acc);
}

__global__ void k_edges_out(const int* __restrict__ src, const int* __restrict__ dst,
                            const int* __restrict__ lab, float* __restrict__ out_ei, int E) {
  int e = blockIdx.x * blockDim.x + threadIdx.x;
  if (e >= E) return;
  out_ei[e] = (float)lab[src[e]];
  out_ei[E + e] = (float)lab[dst[e]];
}

__global__ void k_nodes_out(const int* __restrict__ lab, const int* __restrict__ batch,
                            float* __restrict__ out_cluster, float* __restrict__ out_batch,
                            int N) {
  int i = blockIdx.x * blockDim.x + threadIdx.x;
  if (i >= N) return;
  int c = lab[i];
  out_cluster[i] = (float)c;
  // jnp .at[cluster].set(batch): XLA applies updates in order -> last wins;
  // batch sorted ascending -> last == max. Nonneg float bits are order-isomorphic.
  atomicMax((int*)&out_batch[c], __float_as_int((float)batch[i]));
}

extern "C" void kernel_launch(void* const* d_in, const int* in_sizes, int n_in,
                              void* d_out, int out_size, void* d_ws, size_t ws_size,
                              hipStream_t stream) {
  const float* x = (const float*)d_in[0];
  const int* ei = (const int*)d_in[1];
  const int* batch = (const int*)d_in[2];
  const float* w = (const float*)d_in[3];
  const float* b = (const float*)d_in[4];
  const int N = in_sizes[2];
  const int E = in_sizes[1] / 2;
  const int* src = ei;
  const int* dst = ei + E;

  char* ws = (char*)d_ws;
  size_t off = 0;
  auto alloc = [&](size_t bytes) -> void* {
    void* p = ws + off;
    off = (off + bytes + 255) & ~(size_t)255;
    return p;
  };
  float* sx = (float*)alloc((size_t)N * Cc * 4);
  int* deg = (int*)alloc((size_t)N * 4);
  int* count = (int*)alloc(256);
  const size_t zero_bytes = off;  // sx + deg + count zeroed together
  float* xw1 = (float*)alloc((size_t)N * 4);
  float* xw2 = (float*)alloc((size_t)N * 4);
  float* score = (float*)alloc((size_t)E * 4);
  int* lab = (int*)alloc((size_t)N * 4);
  int2* cedge = (int2*)alloc((size_t)E * 8);
  const int use_compact = (off <= ws_size) ? 1 : 0;

  float* out_x = (float*)d_out;
  float* out_ei = out_x + (size_t)N * Cc;
  float* out_batch = out_ei + 2 * (size_t)E;
  float* out_cluster = out_batch + N;

  hipMemsetAsync(d_out, 0, (size_t)out_size * 4, stream);
  hipMemsetAsync(d_ws, 0, zero_bytes, stream);

  k_node_dots<<<(N + 3) / 4, 256, 0, stream>>>(x, w, b, xw1, xw2, N);
  k_edge_score<<<(E + 255) / 256, 256, 0, stream>>>(src, dst, xw1, xw2, score, cedge, count,
                                                    deg, E, use_compact);
  k_iota<<<(N + 255) / 256, 256, 0, stream>>>(lab, N);
  for (int it = 0; it < 20; ++it) {
    if (use_compact)
      k_relax<<<(E + 255) / 256, 256, 0, stream>>>(cedge, count, lab);
    else
      k_relax_full<<<(E + 255) / 256, 256, 0, stream>>>(src, dst, score, lab, E);
    k_jump<<<(N + 255) / 256, 256, 0, stream>>>(lab, N);
  }
  k_sx<<<(E + 3) / 4, 256, 0, stream>>>(src, dst, score, x, sx, E);
  k_segsum<<<dim3((N + 127) / 128, 2), 64, 0, stream>>>(sx, x, lab, deg, out_x, N);
  k_edges_out<<<(E + 255) / 256, 256, 0, stream>>>(src, dst, lab, out_ei, E);
  k_nodes_out<<<(N + 255) / 256, 256, 0, stream>>>(lab, batch, out_cluster, out_batch, N);
}

// Round 10
// 736.662 us; speedup vs baseline: 1.8578x; 1.8578x over previous
//
#include <hip/hip_runtime.h>

#define WAVE 64
constexpr int Cc = 128;  // in_channels (fixed by problem: C=128)

// ---------------- per-node dot products: xw1[u] = x[u]·w[0:C] + b, xw2[u] = x[u]·w[C:2C]
__global__ void k_node_dots(const float* __restrict__ x, const float* __restrict__ w,
                            const float* __restrict__ bptr, float* __restrict__ xw1,
                            float* __restrict__ xw2, int N) {
  int wid = (blockIdx.x * blockDim.x + threadIdx.x) >> 6;
  int lane = threadIdx.x & (WAVE - 1);
  if (wid >= N) return;
  const float* xr = x + (size_t)wid * Cc;
  float a = xr[lane], c2 = xr[lane + 64];
  float s1 = a * w[lane] + c2 * w[lane + 64];
  float s2 = a * w[lane + 128] + c2 * w[lane + 192];
#pragma unroll
  for (int off = 32; off >= 1; off >>= 1) {
    s1 += __shfl_xor(s1, off);
    s2 += __shfl_xor(s2, off);
  }
  if (lane == 0) {
    xw1[wid] = s1 + bptr[0];
    xw2[wid] = s2;
  }
}

// ---------------- edge scores + contracted-edge compaction + degrees + src counts
__global__ void k_edge_score(const int* __restrict__ src, const int* __restrict__ dst,
                             const float* __restrict__ xw1, const float* __restrict__ xw2,
                             float* __restrict__ score, int2* __restrict__ cedge,
                             int* __restrict__ count, int* __restrict__ deg,
                             int* __restrict__ cnt_src, int E, int do_compact) {
  int e = blockIdx.x * blockDim.x + threadIdx.x;
  int lane = threadIdx.x & 63;
  int s = 0, d = 0;
  bool con = false;
  if (e < E) {
    s = src[e];
    d = dst[e];
    float arg = xw1[s] + xw2[d];  // xw1 already includes bias
    score[e] = tanhf(arg);
    con = arg > 0.0f;  // tanh(arg) > 0  <=>  arg > 0 (exact)
    atomicAdd(&cnt_src[s], 1);   // CSR counts over ALL edges
    if (con) {
      atomicAdd(&deg[s], 1);
      atomicAdd(&deg[d], 1);
    }
  }
  if (!do_compact) return;
  unsigned long long m = __ballot(con);
  int cnt = __popcll(m);
  if (cnt == 0) return;
  int leader = __ffsll((unsigned long long)m) - 1;
  int base = 0;
  if (lane == leader) base = atomicAdd(count, cnt);
  base = __shfl(base, leader);
  if (con) {
    int pfx = __popcll(m & ((1ull << lane) - 1ull));
    cedge[base + pfx] = make_int2(s, d);
  }
}

__global__ void k_iota(int* __restrict__ lab, int N) {
  int i = blockIdx.x * blockDim.x + threadIdx.x;
  if (i < N) lab[i] = i;
}

// fused relax+jump: one launch per CC iteration. Monotone atomicMin => any interleave
// converges to the same fixed point (min node index per component).
__global__ void k_cc_pass(const int2* __restrict__ ce, const int* __restrict__ count,
                          int* __restrict__ lab, int N) {
  int i = blockIdx.x * blockDim.x + threadIdx.x;
  int M = *count;
  if (i < M) {
    int2 p = ce[i];
    int a = lab[p.x], b = lab[p.y];
    if (a < b) atomicMin(&lab[p.y], a);
    else if (b < a) atomicMin(&lab[p.x], b);
  }
  if (i < N) {
    int a = lab[i];
    int b = lab[a];
    if (b < a) atomicMin(&lab[i], b);
  }
}

// fallback without compaction
__global__ void k_cc_pass_full(const int* __restrict__ src, const int* __restrict__ dst,
                               const float* __restrict__ score, int* __restrict__ lab,
                               int E, int N) {
  int i = blockIdx.x * blockDim.x + threadIdx.x;
  if (i < E && score[i] > 0.0f) {
    int a = lab[src[i]], b = lab[dst[i]];
    if (a < b) atomicMin(&lab[dst[i]], a);
    else if (b < a) atomicMin(&lab[src[i]], b);
  }
  if (i < N) {
    int a = lab[i];
    int b = lab[a];
    if (b < a) atomicMin(&lab[i], b);
  }
}

// ---------------- CSR build: exclusive scan of cnt_src (single block, 1024 threads)
__global__ void k_scan(const int* __restrict__ cnt, int* __restrict__ off_arr,
                       int* __restrict__ cursor, int N) {
  __shared__ int part[1024];
  int t = threadIdx.x;
  int chunk = (N + 1023) / 1024;
  int lo = t * chunk, hi = min(lo + chunk, N);
  int s = 0;
  for (int i = lo; i < hi; ++i) s += cnt[i];
  part[t] = s;
  __syncthreads();
  for (int d = 1; d < 1024; d <<= 1) {
    int v = (t >= d) ? part[t - d] : 0;
    __syncthreads();
    part[t] += v;
    __syncthreads();
  }
  int run = (t == 0) ? 0 : part[t - 1];
  for (int i = lo; i < hi; ++i) {
    off_arr[i] = run;
    cursor[i] = run;
    run += cnt[i];
  }
}

__global__ void k_scatter(const int* __restrict__ src, const int* __restrict__ dst,
                          const float* __restrict__ score, int* __restrict__ cursor,
                          int2* __restrict__ pack, int E) {
  int e = blockIdx.x * blockDim.x + threadIdx.x;
  if (e >= E) return;
  int slot = atomicAdd(&cursor[src[e]], 1);
  pack[slot] = make_int2(dst[e], __float_as_int(score[e]));
}

// gather: sx[u] = sum_{edges (u,v)} score * x[v]  (+ x[u] if contracted-degree 0)
// non-atomic full-row store. One wave per node.
__global__ void k_sx_csr(const int2* __restrict__ pack, const int* __restrict__ off_arr,
                         const int* __restrict__ cnt_src, const int* __restrict__ deg,
                         const float* __restrict__ x, float* __restrict__ sx, int N) {
  int wid = (blockIdx.x * blockDim.x + threadIdx.x) >> 6;
  int lane = threadIdx.x & 63;
  if (wid >= N) return;
  int beg = off_arr[wid], num = cnt_src[wid];
  float a0 = 0.f, a1 = 0.f;
  for (int k = 0; k < num; ++k) {
    int2 p = pack[beg + k];
    float t = __int_as_float(p.y);
    const float* xr = x + (size_t)p.x * Cc;
    a0 += t * xr[lane];
    a1 += t * xr[lane + 64];
  }
  if (deg[wid] == 0) {
    const float* xr = x + (size_t)wid * Cc;
    a0 += xr[lane];
    a1 += xr[lane + 64];
  }
  float* sr = sx + (size_t)wid * Cc;
  sr[lane] = a0;
  sr[lane + 64] = a1;
}

// fallback: sx[src] += score * x[dst] via atomics (needs sx pre-zeroed)
__global__ void k_sx_atomic(const int* __restrict__ src, const int* __restrict__ dst,
                            const float* __restrict__ score, const float* __restrict__ x,
                            float* __restrict__ sx, int E) {
  int wid = (blockIdx.x * blockDim.x + threadIdx.x) >> 6;
  int lane = threadIdx.x & 63;
  if (wid >= E) return;
  int s = src[wid], d = dst[wid];
  float t = score[wid];
  const float* xr = x + (size_t)d * Cc;
  float* sr = sx + (size_t)s * Cc;
  atomicAdd(&sr[lane], t * xr[lane]);
  atomicAdd(&sr[lane + 64], t * xr[lane + 64]);
}

// x_out[cluster] += sx (+ x for singles if not already folded), run-length compressed.
// 4 waves/block, 16 nodes per wave, y-dim = column half.
__global__ void k_segsum(const float* __restrict__ sx, const float* __restrict__ x,
                         const int* __restrict__ lab, const int* __restrict__ deg,
                         float* __restrict__ xout, int N, int singles_done) {
  const int CHUNK = 16;
  int wv = threadIdx.x >> 6;
  int lane = threadIdx.x & 63;
  int j = (blockIdx.y << 6) | lane;
  int u0 = (blockIdx.x * 4 + wv) * CHUNK;
  if (u0 >= N) return;
  int u1 = min(u0 + CHUNK, N);
  int prevc = lab[u0];
  float acc = 0.f;
  for (int u = u0; u < u1; ++u) {
    int c = lab[u];
    float v = sx[(size_t)u * Cc + j];
    if (!singles_done && deg[u] == 0) v += x[(size_t)u * Cc + j];
    if (c != prevc) {
      atomicAdd(&xout[(size_t)prevc * Cc + j], acc);
      acc = 0.f;
      prevc = c;
    }
    acc += v;
  }
  atomicAdd(&xout[(size_t)prevc * Cc + j], acc);
}

__global__ void k_edges_out(const int* __restrict__ src, const int* __restrict__ dst,
                            const int* __restrict__ lab, float* __restrict__ out_ei, int E) {
  int e = blockIdx.x * blockDim.x + threadIdx.x;
  if (e >= E) return;
  out_ei[e] = (float)lab[src[e]];
  out_ei[E + e] = (float)lab[dst[e]];
}

// wave-aggregated: one atomicMax per distinct cluster per wave (giant component =>
// ~1 hot atomic per wave instead of 64)
__global__ void k_nodes_out(const int* __restrict__ lab, const int* __restrict__ batch,
                            float* __restrict__ out_cluster, float* __restrict__ out_batch,
                            int N) {
  int i = blockIdx.x * blockDim.x + threadIdx.x;
  int lane = threadIdx.x & 63;
  bool valid = i < N;
  int c = valid ? lab[i] : -1;
  float bv = valid ? (float)batch[i] : -1.f;
  if (valid) out_cluster[i] = (float)c;
  unsigned long long remaining = __ballot(valid);
  while (remaining) {
    int leader = __ffsll((unsigned long long)remaining) - 1;
    int lc = __shfl(c, leader);
    bool mine = valid && (c == lc);
    unsigned long long grp = __ballot(mine);
    float v = mine ? bv : -1.f;
#pragma unroll
    for (int off = 32; off >= 1; off >>= 1) v = fmaxf(v, __shfl_xor(v, off));
    if (lane == leader) atomicMax((int*)&out_batch[lc], __float_as_int(v));
    remaining &= ~grp;
  }
}

extern "C" void kernel_launch(void* const* d_in, const int* in_sizes, int n_in,
                              void* d_out, int out_size, void* d_ws, size_t ws_size,
                              hipStream_t stream) {
  const float* x = (const float*)d_in[0];
  const int* ei = (const int*)d_in[1];
  const int* batch = (const int*)d_in[2];
  const float* w = (const float*)d_in[3];
  const float* b = (const float*)d_in[4];
  const int N = in_sizes[2];
  const int E = in_sizes[1] / 2;
  const int* src = ei;
  const int* dst = ei + E;

  char* ws = (char*)d_ws;
  size_t off = 0;
  auto alloc = [&](size_t bytes) -> void* {
    void* p = ws + off;
    off = (off + bytes + 255) & ~(size_t)255;
    return p;
  };
  int* deg = (int*)alloc((size_t)N * 4);
  int* count = (int*)alloc(256);
  int* cnt_src = (int*)alloc((size_t)N * 4);
  const size_t zero_bytes = off;  // deg + count + cnt_src
  float* sx = (float*)alloc((size_t)N * Cc * 4);
  float* xw1 = (float*)alloc((size_t)N * 4);
  float* xw2 = (float*)alloc((size_t)N * 4);
  float* score = (float*)alloc((size_t)E * 4);
  int* lab = (int*)alloc((size_t)N * 4);
  int* csr_off = (int*)alloc((size_t)N * 4);
  int* cursor = (int*)alloc((size_t)N * 4);
  int2* pack = (int2*)alloc((size_t)E * 8);
  const int use_csr = (off <= ws_size) ? 1 : 0;
  int2* cedge = (int2*)alloc((size_t)E * 8);
  const int use_compact = (off <= ws_size) ? 1 : 0;

  float* out_x = (float*)d_out;
  float* out_ei = out_x + (size_t)N * Cc;
  float* out_batch = out_ei + 2 * (size_t)E;
  float* out_cluster = out_batch + N;

  hipMemsetAsync(d_out, 0, (size_t)out_size * 4, stream);
  hipMemsetAsync(d_ws, 0, zero_bytes, stream);
  if (!use_csr) hipMemsetAsync(sx, 0, (size_t)N * Cc * 4, stream);

  k_node_dots<<<(N + 3) / 4, 256, 0, stream>>>(x, w, b, xw1, xw2, N);
  k_edge_score<<<(E + 255) / 256, 256, 0, stream>>>(src, dst, xw1, xw2, score, cedge, count,
                                                    deg, cnt_src, E, use_compact);
  k_iota<<<(N + 255) / 256, 256, 0, stream>>>(lab, N);
  for (int it = 0; it < 12; ++it) {
    if (use_compact)
      k_cc_pass<<<(E + 255) / 256, 256, 0, stream>>>(cedge, count, lab, N);
    else
      k_cc_pass_full<<<(E + 255) / 256, 256, 0, stream>>>(src, dst, score, lab, E, N);
  }
  if (use_csr) {
    k_scan<<<1, 1024, 0, stream>>>(cnt_src, csr_off, cursor, N);
    k_scatter<<<(E + 255) / 256, 256, 0, stream>>>(src, dst, score, cursor, pack, E);
    k_sx_csr<<<(N + 3) / 4, 256, 0, stream>>>(pack, csr_off, cnt_src, deg, x, sx, N);
  } else {
    k_sx_atomic<<<(E + 3) / 4, 256, 0, stream>>>(src, dst, score, x, sx, E);
  }
  k_segsum<<<dim3((N + 63) / 64, 2), 256, 0, stream>>>(sx, x, lab, deg, out_x, N, use_csr);
  k_edges_out<<<(E + 255) / 256, 256, 0, stream>>>(src, dst, lab, out_ei, E);
  k_nodes_out<<<(N + 255) / 256, 256, 0, stream>>>(lab, batch, out_cluster, out_batch, N);
}